// Round 7
// baseline (89.130 us; speedup 1.0000x reference)
//
#include <hip/hip_runtime.h>

#define IN_F   4096
#define OUT_F  11008
#define BATCH  32
#define NG     32      // K groups of 128
#define PACKS  512     // IN/8 packed ints per output row
#define SLICES 4       // K-partial slices (one per kc chunk)
#define SLICE_F (BATCH * OUT_F)   // floats per partial slice (352256)

typedef __bf16 bf16x8_t __attribute__((ext_vector_type(8)));
typedef float  floatx4_t __attribute__((ext_vector_type(4)));

// signed int4 nibbles (low nibble first) -> 8 exact bf16 values (no scale)
__device__ inline bf16x8_t unpack8(int p) {
  union { unsigned short u[8]; bf16x8_t v; } r;
#pragma unroll
  for (int j = 0; j < 8; ++j) {
    int nib = (p << (28 - 4 * j)) >> 28;             // arithmetic sign-extend
    float f = (float)nib;                            // exact
    r.u[j] = (unsigned short)(__float_as_uint(f) >> 16);  // exact truncation
  }
  return r.v;
}

// ---------------------------------------------------------------------------
// Single fused compute kernel (R6 post-mortem: wql_part pinned at ~17us
// across 3 shapes; residual = dispatch-chain overhead + B latency. This
// folds prep_x into the block as an LDS stage, cutting 3 dispatches -> 2.)
//
// Grid (344 col-tiles) x (4 kc), 512 thr (8 waves). Flow:
//  1. Issue B loads (2 dwordx4/lane from pw, HBM) + scales FIRST so their
//     latency hides under the x-stage.
//  2. Stage x[32][kc*1024..+1024] f32 -> bf16 into LDS. Thread (r=tid/16,
//     s=tid%16), m=0..7 reads 32B f32 at x[r][kc*1024 + s*8 + m*128]
//     (wave = 4 rows x 512B contiguous runs) and writes 16B to unit
//     u = (s + m*16) ^ (r&7)  of row r.  The XOR swizzle breaks the 2KB
//     row-stride bank conflict (16-way without it, G4); both sides use it.
//  3. A-frags via ds_read_b128: wave w (= group), lane (col,q), step t reads
//     unit (w*16 + q*4 + t) ^ (col&7) of rows col / col+16  — bit-identical
//     values to the old xp staging path (same mapping, same RNE cvt).
//  4. 16 MFMAs, fp32 group-scale (verified since R0).
//  5. Park 8 wave-tiles in LDS (reusing the stage region after a barrier),
//     reduce to one 32x32 partial, store to slice kc in d_ws (poisoned
//     unconditionally every iteration — measured R3-R6 — so ws use is free).
// ---------------------------------------------------------------------------
__global__ __launch_bounds__(512) void wql_main(
    const int* __restrict__ pw, const float* __restrict__ scale,
    const float* __restrict__ x, float* __restrict__ part) {
  __shared__ __align__(16) unsigned char lds_raw[65536];
  unsigned short* xs = (unsigned short*)lds_raw;         // [32 rows][128 u][8]
  float* park = (float*)lds_raw;                         // [8][1024], reused

  const int tid = threadIdx.x;
  const int l   = tid & 63;
  const int w   = tid >> 6;        // 0..7 = group index within the kc chunk
  const int col = l & 15;
  const int q   = l >> 4;
  const int n0  = blockIdx.x * 32;
  const int kc  = blockIdx.y;      // 0..3 K-chunk
  const int nA  = n0 + col;        // n-tile 0 column
  const int nB  = n0 + 16 + col;   // n-tile 1 column
  const int gg  = kc * 8 + w;      // this wave's group

  // --- 1. B prefetch: issue before staging so HBM latency overlaps -------
  int4 pA = *(const int4*)(pw + nA * PACKS + gg * 16 + q * 4);
  int4 pB = *(const int4*)(pw + nB * PACKS + gg * 16 + q * 4);
  float sA = scale[nA * NG + gg];
  float sB = scale[nB * NG + gg];

  // --- 2. Stage x slice -> LDS bf16, swizzled ----------------------------
  {
    const int r = tid >> 4, s = tid & 15;
    const float* xrow = x + r * IN_F + kc * 1024 + s * 8;
#pragma unroll
    for (int m = 0; m < 8; ++m) {
      float4 f0 = *(const float4*)(xrow + m * 128);
      float4 f1 = *(const float4*)(xrow + m * 128 + 4);
      bf16x8_t v;
      v[0] = (__bf16)f0.x; v[1] = (__bf16)f0.y;
      v[2] = (__bf16)f0.z; v[3] = (__bf16)f0.w;
      v[4] = (__bf16)f1.x; v[5] = (__bf16)f1.y;
      v[6] = (__bf16)f1.z; v[7] = (__bf16)f1.w;
      int u = (s + m * 16) ^ (r & 7);
      *(bf16x8_t*)(xs + (r * 128 + u) * 8) = v;
    }
  }
  __syncthreads();

  // --- 3. A-frags from LDS (conflict-free via the same swizzle) ----------
  bf16x8_t a0[4], a1[4];
  const int sw = col & 7;          // (col+16)&7 == col&7
#pragma unroll
  for (int t = 0; t < 4; ++t) {
    int u = (w * 16 + q * 4 + t) ^ sw;
    a0[t] = *(const bf16x8_t*)(xs + (col * 128 + u) * 8);         // rows 0..15
    a1[t] = *(const bf16x8_t*)(xs + ((col + 16) * 128 + u) * 8);  // rows 16..31
  }
  __syncthreads();   // all xs reads done before park overwrites the region

  // --- 4. MFMA + group scale (registers only; identical since R0) --------
  floatx4_t t00 = {0.f, 0.f, 0.f, 0.f};
  floatx4_t t01 = {0.f, 0.f, 0.f, 0.f};
  floatx4_t t10 = {0.f, 0.f, 0.f, 0.f};
  floatx4_t t11 = {0.f, 0.f, 0.f, 0.f};
  int pAv[4] = {pA.x, pA.y, pA.z, pA.w};
  int pBv[4] = {pB.x, pB.y, pB.z, pB.w};
#pragma unroll
  for (int t = 0; t < 4; ++t) {
    bf16x8_t b0 = unpack8(pAv[t]);
    bf16x8_t b1 = unpack8(pBv[t]);
    t00 = __builtin_amdgcn_mfma_f32_16x16x32_bf16(a0[t], b0, t00, 0, 0, 0);
    t10 = __builtin_amdgcn_mfma_f32_16x16x32_bf16(a1[t], b0, t10, 0, 0, 0);
    t01 = __builtin_amdgcn_mfma_f32_16x16x32_bf16(a0[t], b1, t01, 0, 0, 0);
    t11 = __builtin_amdgcn_mfma_f32_16x16x32_bf16(a1[t], b1, t11, 0, 0, 0);
  }

  // --- 5. Park this wave's scaled 32x32 tile, reduce 8 tiles, store ------
  // C/D layout: col = lane&15, row = quad*4 + reg   [verified m89/m91]
  float* pk = park + w * 1024;
#pragma unroll
  for (int r = 0; r < 4; ++r) {
    int row = q * 4 + r;
    pk[row * 32 + col]             = t00[r] * sA;
    pk[row * 32 + 16 + col]        = t01[r] * sB;
    pk[(16 + row) * 32 + col]      = t10[r] * sA;
    pk[(16 + row) * 32 + 16 + col] = t11[r] * sB;
  }
  __syncthreads();

  float* wsp = part + kc * SLICE_F + n0;
  for (int e = tid; e < BATCH * 32; e += 512) {
    int row = e >> 5, cl = e & 31;
    float s = park[0 * 1024 + e] + park[1 * 1024 + e]
            + park[2 * 1024 + e] + park[3 * 1024 + e]
            + park[4 * 1024 + e] + park[5 * 1024 + e]
            + park[6 * 1024 + e] + park[7 * 1024 + e];
    wsp[row * OUT_F + cl] = s;
  }
}

// ---------------------------------------------------------------------------
// Stage 2: out = sum of 4 partial slices + bias. Fully-coalesced float4
// reads (5.6 MB, L2/L3-resident), one float4 store per thread.
// ---------------------------------------------------------------------------
__global__ __launch_bounds__(256) void reduce_out(
    const float* __restrict__ part, const float* __restrict__ bias,
    float* __restrict__ out) {
  int e4 = blockIdx.x * 256 + threadIdx.x;   // 0..88063 float4s
  int e  = e4 << 2;
  int o  = e % OUT_F;                        // OUT_F % 4 == 0
  float4 s = *(const float4*)(bias + o);
#pragma unroll
  for (int k = 0; k < SLICES; ++k) {
    float4 p = *(const float4*)(part + k * SLICE_F + e);
    s.x += p.x; s.y += p.y; s.z += p.z; s.w += p.w;
  }
  *(float4*)(out + e) = s;
}

extern "C" void kernel_launch(void* const* d_in, const int* in_sizes, int n_in,
                              void* d_out, int out_size, void* d_ws, size_t ws_size,
                              hipStream_t stream) {
  const float* x     = (const float*)d_in[0];
  const int*   pw    = (const int*)d_in[1];
  const float* scale = (const float*)d_in[2];
  const float* bias  = (const float*)d_in[3];
  float* out = (float*)d_out;
  float* part = (float*)d_ws;                  // 4 x 1.41 MB partial slices

  hipLaunchKernelGGL(wql_main, dim3(OUT_F / 32, 4), dim3(512), 0, stream,
                     pw, scale, x, part);
  hipLaunchKernelGGL(reduce_out, dim3(BATCH * OUT_F / 4 / 256), dim3(256), 0,
                     stream, part, bias, out);
}

// Round 8
// 86.880 us; speedup vs baseline: 1.0259x; 1.0259x over previous
//
#include <hip/hip_runtime.h>

#define IN_F   4096
#define OUT_F  11008
#define BATCH  32
#define NG     32      // K groups of 128
#define PACKS  512     // IN/8 packed ints per output row

typedef __bf16 bf16x8_t __attribute__((ext_vector_type(8)));
typedef float  floatx4_t __attribute__((ext_vector_type(4)));

// ---------------------------------------------------------------------------
// Prep: x fp32 [32,4096] -> bf16, reordered so main-kernel A-fragment loads
// are lane-contiguous 16B/lane (harness-verified since round 0). Chunk c:
//   mm=c&31, q=(c>>5)&3, t=(c>>7)&3, g=c>>9
//   xp[c*8+j] = bf16( x[mm][g*128 + q*32 + t*8 + j] )
// R7 post-mortem: folding this into the main kernel made things WORSE
// (per-block fp32 restage doubled A-bytes + paid cvt 1376x). One-time
// shared reorder is the right amortization point. d_ws poison fill is
// unconditional (measured R3-R7), so ws use is free.
// ---------------------------------------------------------------------------
__global__ __launch_bounds__(256) void prep_x(const float* __restrict__ x,
                                              unsigned short* __restrict__ xp) {
  int c  = blockIdx.x * 256 + threadIdx.x;      // 0..16383
  int mm = c & 31;
  int k0 = ((c >> 5) & 3) * 32 + ((c >> 7) & 3) * 8 + (c >> 9) * 128;
  const float* src = x + mm * IN_F + k0;
  float4 f0 = *(const float4*)(src);
  float4 f1 = *(const float4*)(src + 4);
  float v[8] = {f0.x, f0.y, f0.z, f0.w, f1.x, f1.y, f1.z, f1.w};
  union { unsigned short s[8]; uint4 u; } r;
#pragma unroll
  for (int j = 0; j < 8; ++j) {
    unsigned int u = __float_as_uint(v[j]);
    unsigned int rnd = ((u >> 16) & 1u) + 0x7fffu;   // RNE fp32->bf16
    r.s[j] = (unsigned short)((u + rnd) >> 16);
  }
  *(uint4*)(xp + c * 8) = r.u;
}

// signed int4 nibbles (low nibble first) -> 8 exact bf16 values.
// Magic-float unpack: u=(p>>4j)&0xF; bits (u^8)|0x4B000000 is the float
// 8388608+(u^8); subtracting 8388616 gives (u^8)-8 = signed nibble, EXACT
// (integers < 2^23). bf16 cast of -8..7 is exact. Bit-identical to the old
// shl/ashr/cvt path at ~3.5 VALU/nibble instead of ~4.5.
__device__ inline bf16x8_t unpack8(int p) {
  bf16x8_t r;
#pragma unroll
  for (int j = 0; j < 8; ++j) {
    unsigned int b = (((unsigned int)p >> (4 * j)) & 0xFu) ^ 0x4B000008u;
    r[j] = (__bf16)(__uint_as_float(b) - 8388616.0f);
  }
  return r;
}

// ---------------------------------------------------------------------------
// Single full-K compute kernel (R7 post-mortem: kill stage 2 + its gap +
// 11.2 MB of partial round-trip; fix per-CU imbalance).
// Grid 688 x 16-col tiles, 512 thr (8 waves): wave w computes groups
// 4w..4w+3 over the block's 16 output cols -> K fully covered in-block.
// Per lane per wave the 4 B-int4s span 256B contiguous of pw (full lines).
// A-frags from xp (coalesced 16B/lane, L2-resident). Epilogue: LDS-reduce
// the 8 wave-tiles + bias -> direct out store. 688 blocks / 256 CUs at
// 4 blocks/CU capacity = single cohort, 1.12x max imbalance (vs 2x at 344).
// __launch_bounds__(512,8) pins <=64 VGPR -> full 32 waves/CU.
// ---------------------------------------------------------------------------
__global__ __launch_bounds__(512, 8) void wql_full(
    const int* __restrict__ pw, const float* __restrict__ scale,
    const float* __restrict__ bias, const unsigned short* __restrict__ xp,
    float* __restrict__ out) {
  __shared__ float park[8][BATCH * 16];

  const int tid = threadIdx.x;
  const int l   = tid & 63;
  const int w   = tid >> 6;        // 0..7: this wave's group quartet
  const int col = l & 15;
  const int q   = l >> 4;
  const int n0  = blockIdx.x * 16;
  const int nA  = n0 + col;

  floatx4_t acc0 = {0.f, 0.f, 0.f, 0.f};   // batch rows 0..15
  floatx4_t acc1 = {0.f, 0.f, 0.f, 0.f};   // batch rows 16..31

  // Per-lane B base: 4 consecutive groups = 4 int4s spanning 256B.
  const int* pwp = pw + nA * PACKS + (w * 4) * 16 + q * 4;
  int4 pcur = *(const int4*)(pwp);

#pragma unroll 1
  for (int gi = 0; gi < 4; ++gi) {
    const int gg = w * 4 + gi;
    int4 pnext;
    if (gi < 3) pnext = *(const int4*)(pwp + (gi + 1) * 16);  // prefetch
    float sA = scale[nA * NG + gg];

    // A: chunk = gg*512 + t*128 + q*32 + row; rows row=col / col+16.
    const unsigned short* ab = xp + (gg * 512 + q * 32 + col) * 8;
    bf16x8_t a0[4], a1[4];
#pragma unroll
    for (int t = 0; t < 4; ++t) {
      a0[t] = *(const bf16x8_t*)(ab + t * 1024);        // rows 0..15
      a1[t] = *(const bf16x8_t*)(ab + t * 1024 + 128);  // rows 16..31
    }

    floatx4_t t0 = {0.f, 0.f, 0.f, 0.f};
    floatx4_t t1 = {0.f, 0.f, 0.f, 0.f};
    int pv[4] = {pcur.x, pcur.y, pcur.z, pcur.w};
#pragma unroll
    for (int t = 0; t < 4; ++t) {
      bf16x8_t b = unpack8(pv[t]);
      t0 = __builtin_amdgcn_mfma_f32_16x16x32_bf16(a0[t], b, t0, 0, 0, 0);
      t1 = __builtin_amdgcn_mfma_f32_16x16x32_bf16(a1[t], b, t1, 0, 0, 0);
    }
    // fp32 group scale (col == lane&15 == C/D col for all regs)
#pragma unroll
    for (int r = 0; r < 4; ++r) {
      acc0[r] += t0[r] * sA;
      acc1[r] += t1[r] * sA;
    }
    pcur = pnext;
  }

  // Park this wave's 32x16 tile.
  // C/D layout: col = lane&15, row = quad*4 + reg   [verified m89/m91]
#pragma unroll
  for (int r = 0; r < 4; ++r) {
    int row = q * 4 + r;
    park[w][row * 16 + col]        = acc0[r];
    park[w][(16 + row) * 16 + col] = acc1[r];
  }
  __syncthreads();

  // 512 threads, 512 elements: reduce 8 wave-tiles + bias -> out.
  {
    int e = tid;                   // 0..511
    int row = e >> 4, cl = e & 15;
    float s = park[0][e] + park[1][e] + park[2][e] + park[3][e]
            + park[4][e] + park[5][e] + park[6][e] + park[7][e]
            + bias[n0 + cl];
    out[row * OUT_F + n0 + cl] = s;
  }
}

extern "C" void kernel_launch(void* const* d_in, const int* in_sizes, int n_in,
                              void* d_out, int out_size, void* d_ws, size_t ws_size,
                              hipStream_t stream) {
  const float* x     = (const float*)d_in[0];
  const int*   pw    = (const int*)d_in[1];
  const float* scale = (const float*)d_in[2];
  const float* bias  = (const float*)d_in[3];
  float* out = (float*)d_out;
  unsigned short* xp = (unsigned short*)d_ws;   // 256 KiB bf16 staging

  hipLaunchKernelGGL(prep_x, dim3(16384 / 256), dim3(256), 0, stream, x, xp);
  hipLaunchKernelGGL(wql_full, dim3(OUT_F / 16), dim3(512), 0, stream,
                     pw, scale, bias, xp, out);
}